// Round 1
// baseline (1157.254 us; speedup 1.0000x reference)
//
#include <hip/hip_runtime.h>

// SSIM on (32,3,512,512) f32 — wave-autonomous separable 11-tap streaming.
// R8: (1) shift-register vertical conv (descending FMA chain, period-1 code,
// no rotation unroll -> ~8KB hot body); (2) fully branchless hot loop:
// unconditional clamped loads + multiply-by-validity at consume, so the
// waitcnt pass keeps precise vmcnt and the depth-3 register prefetch ring
// actually pipelines (R7's guarded loads forced vmcnt(0) every step);
// (3) LDS packed float4 (xA,xB,yA,yB) -> 7 ds_read_b128/step (was 14 b64);
// (4) 256-thread blocks = 4 wave-private bands sharing one I-stream.
// Each wave: 128 cols x 64 rows; lanes hold 2 cols. No hot-loop barriers.
// R9: __launch_bounds__(256,4). Counters showed the two-phase dispatch
// (512 blocks @ 8 waves/CU, then 256 @ 4) averaging 18% occupancy / 51%
// VALUBusy with VGPR=120 (<=128, so 4 waves/SIMD is free). 4 blocks/CU
// makes all 768 blocks co-resident (12 waves/CU, zero tail).

#define NBLK 768

__device__ __forceinline__ float2 f2z() { return make_float2(0.f, 0.f); }
__device__ __forceinline__ float2 fma2(float s, float2 a, float2 c) {
    return make_float2(fmaf(s, a.x, c.x), fmaf(s, a.y, c.y));
}
__device__ __forceinline__ float2 mul2(float s, float2 a) {
    return make_float2(s * a.x, s * a.y);
}

// ---- vertical shift-register chains: 10 regs x 5 quantities (float2 A/B) ----
#define DECL_CH(C) float2 C##0=f2z(),C##1=f2z(),C##2=f2z(),C##3=f2z(),C##4=f2z(), \
                          C##5=f2z(),C##6=f2z(),C##7=f2z(),C##8=f2z(),C##9=f2z();
// descending: each reads the not-yet-overwritten lower element
#define SHIFT(C, H) \
  C##9 = fma2(g9, H, C##8); C##8 = fma2(g8, H, C##7); C##7 = fma2(g7, H, C##6); \
  C##6 = fma2(g6, H, C##5); C##5 = fma2(g5, H, C##4); C##4 = fma2(g4, H, C##3); \
  C##3 = fma2(g3, H, C##2); C##2 = fma2(g2, H, C##1); C##1 = fma2(g1, H, C##0); \
  C##0 = mul2(g0, H);

// ---- horizontal tap J: colA uses val[J+1], colB val[J+2] ----
#define HTAP(J, UA, UB) { const float gj = g##J; \
  { const float xv = XV##UA, yv = YV##UA; const float t1 = gj*xv, t2 = gj*yv; \
    HX.x += t1; HY.x += t2; HXX.x = fmaf(t1,xv,HXX.x); HYY.x = fmaf(t2,yv,HYY.x); HXY.x = fmaf(t1,yv,HXY.x); } \
  { const float xv = XV##UB, yv = YV##UB; const float t1 = gj*xv, t2 = gj*yv; \
    HX.y += t1; HY.y += t2; HXX.y = fmaf(t1,xv,HXX.y); HYY.y = fmaf(t2,yv,HYY.y); HXY.y = fmaf(t1,yv,HXY.y); } }

#define SSIM_COL(MU_X, MU_Y, SXX, SYY, SXY, TS) { \
  const float mux = MU_X, muy = MU_Y; \
  const float mux2 = mux*mux, muy2 = muy*muy, muxy = mux*muy; \
  const float vvx = SXX - mux2, vvy = SYY - muy2, vxy = SXY - muxy; \
  const float num = fmaf(2.f, muxy, C1) * fmaf(2.f, vxy, C2); \
  const float den = (mux2 + muy2 + C1) * (vvx + vvy + C2); \
  TS += num * __builtin_amdgcn_rcpf(den); }

// One step: issue PF slot P (row r0-2+i), compute h-conv of current LDS row,
// chain-shift, emit if 10<=i<74, then store PF slot Q (issued 2 steps ago).
#define STEP(I, P, Q) { \
  const int i_ = (I); \
  const int rl = r0 - 2 + i_; \
  VM##P = ((unsigned)rl < 512u) ? 1.f : 0.f; \
  { const int rlc = (rl < 0) ? 0 : ((rl > 511) ? 511 : rl); \
    const float* xp = xplane + (rlc << 9); \
    const float* yp = yplane + (rlc << 9); \
    PF##P##mx = *(const float2*)(xp + mcol); PF##P##my = *(const float2*)(yp + mcol); \
    PF##P##hx = *(const float2*)(xp + hcolC); PF##P##hy = *(const float2*)(yp + hcolC); } \
  const float4 q0 = lsw[lane  ], q1 = lsw[lane+1], q2 = lsw[lane+2], q3 = lsw[lane+3]; \
  const float4 q4 = lsw[lane+4], q5 = lsw[lane+5], q6 = lsw[lane+6]; \
  const float XV1 = q0.y, XV2 = q1.x, XV3 = q1.y, XV4 = q2.x, XV5 = q2.y, XV6 = q3.x; \
  const float XV7 = q3.y, XV8 = q4.x, XV9 = q4.y, XV10 = q5.x, XV11 = q5.y, XV12 = q6.x; \
  const float YV1 = q0.w, YV2 = q1.z, YV3 = q1.w, YV4 = q2.z, YV5 = q2.w, YV6 = q3.z; \
  const float YV7 = q3.w, YV8 = q4.z, YV9 = q4.w, YV10 = q5.z, YV11 = q5.w, YV12 = q6.z; \
  float2 HX = f2z(), HY = f2z(), HXX = f2z(), HYY = f2z(), HXY = f2z(); \
  HTAP(0,1,2)  HTAP(1,2,3)  HTAP(2,3,4)  HTAP(3,4,5)  HTAP(4,5,6)  HTAP(5,6,7) \
  HTAP(6,7,8)  HTAP(7,8,9)  HTAP(8,9,10) HTAP(9,10,11) HTAP(10,11,12) \
  if (i_ >= 10 && i_ < 74) { \
    const float2 EX  = fma2(g10, HX , CX9 ); \
    const float2 EY  = fma2(g10, HY , CY9 ); \
    const float2 EXX = fma2(g10, HXX, CXX9); \
    const float2 EYY = fma2(g10, HYY, CYY9); \
    const float2 EXY = fma2(g10, HXY, CXY9); \
    SSIM_COL(EX.x, EY.x, EXX.x, EYY.x, EXY.x, tsx) \
    SSIM_COL(EX.y, EY.y, EXX.y, EYY.y, EXY.y, tsy) \
  } \
  SHIFT(CX, HX) SHIFT(CY, HY) SHIFT(CXX, HXX) SHIFT(CYY, HYY) SHIFT(CXY, HXY) \
  { const float fq = VM##Q; const float fh = fq * hmask; \
    const float2 wmx = mul2(fq, PF##Q##mx), wmy = mul2(fq, PF##Q##my); \
    const float2 whx = mul2(fh, PF##Q##hx), why = mul2(fh, PF##Q##hy); \
    lsw[lane + 3] = make_float4(wmx.x, wmx.y, wmy.x, wmy.y); \
    if (lane < 6) lsw[hslot] = make_float4(whx.x, whx.y, why.x, why.y); } }

__global__ __launch_bounds__(256, 4) void ssim_fused(
    const float* __restrict__ x, const float* __restrict__ y,
    const float* __restrict__ window,
    unsigned* __restrict__ counter, float* __restrict__ partials,
    float* __restrict__ out)
{
    const int tid  = threadIdx.x;
    const int lane = tid & 63;
    const int wv   = tid >> 6;
    const int W    = blockIdx.x * 4 + wv;   // 0..3071
    const int img  = W >> 5;                // 96 planes
    const int cb   = (W >> 3) & 3;          // 4 col bands x 128
    const int rb   = W & 7;                 // 8 row bands x 64
    const int r0   = rb << 6;
    const int c0   = cb << 7;

    const float* xplane = x + (size_t)img * 262144;
    const float* yplane = y + (size_t)img * 262144;

    // halo geometry (time-invariant): slots 0..2 left, 67..69 right
    const int  hslot = (lane < 3) ? lane : (64 + lane);
    const int  hcol  = (lane < 3) ? (c0 - 6 + 2 * lane)
                                  : (c0 + 128 + 2 * (lane - 3));
    const float hmask = (lane < 6 && hcol >= 0 && hcol < 511) ? 1.f : 0.f;
    const int  hcolC = (hcol < 0) ? 0 : ((hcol > 510) ? 510 : hcol);
    const int  mcol  = c0 + 2 * lane;

    // 1-D gaussian (row sums of outer(g,g)); uniform -> SGPR via readfirstlane
    float gtmp[11];
    #pragma unroll
    for (int ii = 0; ii < 11; ++ii) {
        float s = 0.f;
        #pragma unroll
        for (int jj = 0; jj < 11; ++jj) s += window[ii * 11 + jj];
        gtmp[ii] = s;
    }
    #define SG(N) const float g##N = __uint_as_float(__builtin_amdgcn_readfirstlane(__float_as_uint(gtmp[N])));
    SG(0) SG(1) SG(2) SG(3) SG(4) SG(5) SG(6) SG(7) SG(8) SG(9) SG(10)

    // wave-private LDS row: slot k = float4(xA,xB,yA,yB) for cols c0-6+2k,+1
    __shared__ float4 ls4[4][72];
    float4* lsw = ls4[wv];

    DECL_CH(CX) DECL_CH(CY) DECL_CH(CXX) DECL_CH(CYY) DECL_CH(CXY)

    // prefetch ring state
    float2 PF0mx, PF0my, PF0hx, PF0hy; float VM0 = 0.f;
    float2 PF1mx, PF1my, PF1hx, PF1hy; float VM1;
    float2 PF2mx, PF2my, PF2hx, PF2hy; float VM2;

    // prime LDS with row r0-5 (read at step 0)
    {
        const int rl = r0 - 5;
        const float fq = ((unsigned)rl < 512u) ? 1.f : 0.f;
        const int rlc = (rl < 0) ? 0 : rl;
        const float* xp = xplane + (rlc << 9);
        const float* yp = yplane + (rlc << 9);
        const float2 mx = *(const float2*)(xp + mcol), my = *(const float2*)(yp + mcol);
        const float2 hx = *(const float2*)(xp + hcolC), hy = *(const float2*)(yp + hcolC);
        const float fh = fq * hmask;
        const float2 wmx = mul2(fq, mx), wmy = mul2(fq, my);
        const float2 whx = mul2(fh, hx), why = mul2(fh, hy);
        lsw[lane + 3] = make_float4(wmx.x, wmx.y, wmy.x, wmy.y);
        if (lane < 6) lsw[hslot] = make_float4(whx.x, whx.y, why.x, why.y);
    }
    // prime PF1 <- row r0-4 (stored end of step 0), PF2 <- row r0-3 (step 1)
    {
        const int rl = r0 - 4;
        VM1 = ((unsigned)rl < 512u) ? 1.f : 0.f;
        const int rlc = (rl < 0) ? 0 : rl;
        const float* xp = xplane + (rlc << 9);
        const float* yp = yplane + (rlc << 9);
        PF1mx = *(const float2*)(xp + mcol); PF1my = *(const float2*)(yp + mcol);
        PF1hx = *(const float2*)(xp + hcolC); PF1hy = *(const float2*)(yp + hcolC);
    }
    {
        const int rl = r0 - 3;
        VM2 = ((unsigned)rl < 512u) ? 1.f : 0.f;
        const int rlc = (rl < 0) ? 0 : rl;
        const float* xp = xplane + (rlc << 9);
        const float* yp = yplane + (rlc << 9);
        PF2mx = *(const float2*)(xp + mcol); PF2my = *(const float2*)(yp + mcol);
        PF2hx = *(const float2*)(xp + hcolC); PF2hy = *(const float2*)(yp + hcolC);
    }

    float tsx = 0.f, tsy = 0.f;
    const float C1 = 1e-4f, C2 = 9e-4f;

    // 75 steps = 25 x 3 (PF ring period); emits for i in [10,74)
    #pragma unroll 1
    for (int it = 0; it < 25; ++it) {
        const int i0 = it * 3;
        STEP(i0 + 0, 0, 1)
        STEP(i0 + 1, 1, 2)
        STEP(i0 + 2, 2, 0)
    }

    // ---- block partial -> global; last block reduces all ----
    float t = tsx + tsy;
    #pragma unroll
    for (int off = 32; off > 0; off >>= 1) t += __shfl_down(t, off, 64);
    __shared__ float wsum[4];
    __shared__ int   sflag;
    if (lane == 0) wsum[wv] = t;
    __syncthreads();
    if (tid == 0) {
        partials[blockIdx.x] = (wsum[0] + wsum[1]) + (wsum[2] + wsum[3]);
        __threadfence();
        const unsigned old = atomicAdd(counter, 1u);
        sflag = (old == NBLK - 1) ? 1 : 0;
    }
    __syncthreads();
    if (sflag) {
        __threadfence();
        double s = 0.0;
        for (int idx = tid; idx < NBLK; idx += 256) s += (double)partials[idx];
        #pragma unroll
        for (int off = 32; off > 0; off >>= 1) s += __shfl_down(s, off, 64);
        __shared__ double dsum[4];
        if (lane == 0) dsum[wv] = s;
        __syncthreads();
        if (tid == 0)
            out[0] = (float)(((dsum[0] + dsum[1]) + (dsum[2] + dsum[3])) / 25165824.0);
    }
}

extern "C" void kernel_launch(void* const* d_in, const int* in_sizes, int n_in,
                              void* d_out, int out_size, void* d_ws, size_t ws_size,
                              hipStream_t stream)
{
    const float* x = (const float*)d_in[0];
    const float* y = (const float*)d_in[1];
    const float* w = (const float*)d_in[2];
    unsigned* counter = (unsigned*)d_ws;                     // zeroed below
    float* partials   = (float*)((char*)d_ws + 256);         // 768 floats

    hipMemsetAsync(d_ws, 0, 4, stream);                      // capture-safe
    ssim_fused<<<NBLK, 256, 0, stream>>>(x, y, w, counter, partials, (float*)d_out);
}

// Round 2
// 785.012 us; speedup vs baseline: 1.4742x; 1.4742x over previous
//
#include <hip/hip_runtime.h>

// SSIM on (32,3,512,512) f32 — wave-autonomous separable 11-tap streaming.
// R8: (1) shift-register vertical conv (descending FMA chain, period-1 code,
// no rotation unroll -> ~8KB hot body); (2) fully branchless hot loop:
// unconditional clamped loads + multiply-by-validity at consume, so the
// waitcnt pass keeps precise vmcnt and the depth-3 register prefetch ring
// actually pipelines; (3) LDS packed float4 (xA,xB,yA,yB) -> 7
// ds_read_b128/step; (4) 256-thread blocks = 4 wave-private bands.
// Each wave: 128 cols x 64 rows; lanes hold 2 cols. No hot-loop barriers.
// R9 FAILED: __launch_bounds__(256,4) budgets 128 VGPR; the ~120-reg live set
// spilled (VGPR 120->64, 3GB scratch traffic, 7x slower). Lesson: the spill
// cliff is between the 170-reg (3 waves/EU) and 128-reg (4 waves/EU) budgets.
// R10: __launch_bounds__(256,3) — 170-reg budget (no spill possible at 120),
// declares 3 blocks/CU so all 768 blocks co-resident (12 waves/CU, one
// phase, zero tail). R1's counters validated OccupancyPercent: 34.5% ~=
// launch-limited 37.5%, so R0's 18% under (256,2) was a real 2-blocks/CU cap.

#define NBLK 768

__device__ __forceinline__ float2 f2z() { return make_float2(0.f, 0.f); }
__device__ __forceinline__ float2 fma2(float s, float2 a, float2 c) {
    return make_float2(fmaf(s, a.x, c.x), fmaf(s, a.y, c.y));
}
__device__ __forceinline__ float2 mul2(float s, float2 a) {
    return make_float2(s * a.x, s * a.y);
}

// ---- vertical shift-register chains: 10 regs x 5 quantities (float2 A/B) ----
#define DECL_CH(C) float2 C##0=f2z(),C##1=f2z(),C##2=f2z(),C##3=f2z(),C##4=f2z(), \
                          C##5=f2z(),C##6=f2z(),C##7=f2z(),C##8=f2z(),C##9=f2z();
// descending: each reads the not-yet-overwritten lower element
#define SHIFT(C, H) \
  C##9 = fma2(g9, H, C##8); C##8 = fma2(g8, H, C##7); C##7 = fma2(g7, H, C##6); \
  C##6 = fma2(g6, H, C##5); C##5 = fma2(g5, H, C##4); C##4 = fma2(g4, H, C##3); \
  C##3 = fma2(g3, H, C##2); C##2 = fma2(g2, H, C##1); C##1 = fma2(g1, H, C##0); \
  C##0 = mul2(g0, H);

// ---- horizontal tap J: colA uses val[J+1], colB val[J+2] ----
#define HTAP(J, UA, UB) { const float gj = g##J; \
  { const float xv = XV##UA, yv = YV##UA; const float t1 = gj*xv, t2 = gj*yv; \
    HX.x += t1; HY.x += t2; HXX.x = fmaf(t1,xv,HXX.x); HYY.x = fmaf(t2,yv,HYY.x); HXY.x = fmaf(t1,yv,HXY.x); } \
  { const float xv = XV##UB, yv = YV##UB; const float t1 = gj*xv, t2 = gj*yv; \
    HX.y += t1; HY.y += t2; HXX.y = fmaf(t1,xv,HXX.y); HYY.y = fmaf(t2,yv,HYY.y); HXY.y = fmaf(t1,yv,HXY.y); } }

#define SSIM_COL(MU_X, MU_Y, SXX, SYY, SXY, TS) { \
  const float mux = MU_X, muy = MU_Y; \
  const float mux2 = mux*mux, muy2 = muy*muy, muxy = mux*muy; \
  const float vvx = SXX - mux2, vvy = SYY - muy2, vxy = SXY - muxy; \
  const float num = fmaf(2.f, muxy, C1) * fmaf(2.f, vxy, C2); \
  const float den = (mux2 + muy2 + C1) * (vvx + vvy + C2); \
  TS += num * __builtin_amdgcn_rcpf(den); }

// One step: issue PF slot P (row r0-2+i), compute h-conv of current LDS row,
// chain-shift, emit if 10<=i<74, then store PF slot Q (issued 2 steps ago).
#define STEP(I, P, Q) { \
  const int i_ = (I); \
  const int rl = r0 - 2 + i_; \
  VM##P = ((unsigned)rl < 512u) ? 1.f : 0.f; \
  { const int rlc = (rl < 0) ? 0 : ((rl > 511) ? 511 : rl); \
    const float* xp = xplane + (rlc << 9); \
    const float* yp = yplane + (rlc << 9); \
    PF##P##mx = *(const float2*)(xp + mcol); PF##P##my = *(const float2*)(yp + mcol); \
    PF##P##hx = *(const float2*)(xp + hcolC); PF##P##hy = *(const float2*)(yp + hcolC); } \
  const float4 q0 = lsw[lane  ], q1 = lsw[lane+1], q2 = lsw[lane+2], q3 = lsw[lane+3]; \
  const float4 q4 = lsw[lane+4], q5 = lsw[lane+5], q6 = lsw[lane+6]; \
  const float XV1 = q0.y, XV2 = q1.x, XV3 = q1.y, XV4 = q2.x, XV5 = q2.y, XV6 = q3.x; \
  const float XV7 = q3.y, XV8 = q4.x, XV9 = q4.y, XV10 = q5.x, XV11 = q5.y, XV12 = q6.x; \
  const float YV1 = q0.w, YV2 = q1.z, YV3 = q1.w, YV4 = q2.z, YV5 = q2.w, YV6 = q3.z; \
  const float YV7 = q3.w, YV8 = q4.z, YV9 = q4.w, YV10 = q5.z, YV11 = q5.w, YV12 = q6.z; \
  float2 HX = f2z(), HY = f2z(), HXX = f2z(), HYY = f2z(), HXY = f2z(); \
  HTAP(0,1,2)  HTAP(1,2,3)  HTAP(2,3,4)  HTAP(3,4,5)  HTAP(4,5,6)  HTAP(5,6,7) \
  HTAP(6,7,8)  HTAP(7,8,9)  HTAP(8,9,10) HTAP(9,10,11) HTAP(10,11,12) \
  if (i_ >= 10 && i_ < 74) { \
    const float2 EX  = fma2(g10, HX , CX9 ); \
    const float2 EY  = fma2(g10, HY , CY9 ); \
    const float2 EXX = fma2(g10, HXX, CXX9); \
    const float2 EYY = fma2(g10, HYY, CYY9); \
    const float2 EXY = fma2(g10, HXY, CXY9); \
    SSIM_COL(EX.x, EY.x, EXX.x, EYY.x, EXY.x, tsx) \
    SSIM_COL(EX.y, EY.y, EXX.y, EYY.y, EXY.y, tsy) \
  } \
  SHIFT(CX, HX) SHIFT(CY, HY) SHIFT(CXX, HXX) SHIFT(CYY, HYY) SHIFT(CXY, HXY) \
  { const float fq = VM##Q; const float fh = fq * hmask; \
    const float2 wmx = mul2(fq, PF##Q##mx), wmy = mul2(fq, PF##Q##my); \
    const float2 whx = mul2(fh, PF##Q##hx), why = mul2(fh, PF##Q##hy); \
    lsw[lane + 3] = make_float4(wmx.x, wmx.y, wmy.x, wmy.y); \
    if (lane < 6) lsw[hslot] = make_float4(whx.x, whx.y, why.x, why.y); } }

__global__ __launch_bounds__(256, 3) void ssim_fused(
    const float* __restrict__ x, const float* __restrict__ y,
    const float* __restrict__ window,
    unsigned* __restrict__ counter, float* __restrict__ partials,
    float* __restrict__ out)
{
    const int tid  = threadIdx.x;
    const int lane = tid & 63;
    const int wv   = tid >> 6;
    const int W    = blockIdx.x * 4 + wv;   // 0..3071
    const int img  = W >> 5;                // 96 planes
    const int cb   = (W >> 3) & 3;          // 4 col bands x 128
    const int rb   = W & 7;                 // 8 row bands x 64
    const int r0   = rb << 6;
    const int c0   = cb << 7;

    const float* xplane = x + (size_t)img * 262144;
    const float* yplane = y + (size_t)img * 262144;

    // halo geometry (time-invariant): slots 0..2 left, 67..69 right
    const int  hslot = (lane < 3) ? lane : (64 + lane);
    const int  hcol  = (lane < 3) ? (c0 - 6 + 2 * lane)
                                  : (c0 + 128 + 2 * (lane - 3));
    const float hmask = (lane < 6 && hcol >= 0 && hcol < 511) ? 1.f : 0.f;
    const int  hcolC = (hcol < 0) ? 0 : ((hcol > 510) ? 510 : hcol);
    const int  mcol  = c0 + 2 * lane;

    // 1-D gaussian (row sums of outer(g,g)); uniform -> SGPR via readfirstlane
    float gtmp[11];
    #pragma unroll
    for (int ii = 0; ii < 11; ++ii) {
        float s = 0.f;
        #pragma unroll
        for (int jj = 0; jj < 11; ++jj) s += window[ii * 11 + jj];
        gtmp[ii] = s;
    }
    #define SG(N) const float g##N = __uint_as_float(__builtin_amdgcn_readfirstlane(__float_as_uint(gtmp[N])));
    SG(0) SG(1) SG(2) SG(3) SG(4) SG(5) SG(6) SG(7) SG(8) SG(9) SG(10)

    // wave-private LDS row: slot k = float4(xA,xB,yA,yB) for cols c0-6+2k,+1
    __shared__ float4 ls4[4][72];
    float4* lsw = ls4[wv];

    DECL_CH(CX) DECL_CH(CY) DECL_CH(CXX) DECL_CH(CYY) DECL_CH(CXY)

    // prefetch ring state
    float2 PF0mx, PF0my, PF0hx, PF0hy; float VM0 = 0.f;
    float2 PF1mx, PF1my, PF1hx, PF1hy; float VM1;
    float2 PF2mx, PF2my, PF2hx, PF2hy; float VM2;

    // prime LDS with row r0-5 (read at step 0)
    {
        const int rl = r0 - 5;
        const float fq = ((unsigned)rl < 512u) ? 1.f : 0.f;
        const int rlc = (rl < 0) ? 0 : rl;
        const float* xp = xplane + (rlc << 9);
        const float* yp = yplane + (rlc << 9);
        const float2 mx = *(const float2*)(xp + mcol), my = *(const float2*)(yp + mcol);
        const float2 hx = *(const float2*)(xp + hcolC), hy = *(const float2*)(yp + hcolC);
        const float fh = fq * hmask;
        const float2 wmx = mul2(fq, mx), wmy = mul2(fq, my);
        const float2 whx = mul2(fh, hx), why = mul2(fh, hy);
        lsw[lane + 3] = make_float4(wmx.x, wmx.y, wmy.x, wmy.y);
        if (lane < 6) lsw[hslot] = make_float4(whx.x, whx.y, why.x, why.y);
    }
    // prime PF1 <- row r0-4 (stored end of step 0), PF2 <- row r0-3 (step 1)
    {
        const int rl = r0 - 4;
        VM1 = ((unsigned)rl < 512u) ? 1.f : 0.f;
        const int rlc = (rl < 0) ? 0 : rl;
        const float* xp = xplane + (rlc << 9);
        const float* yp = yplane + (rlc << 9);
        PF1mx = *(const float2*)(xp + mcol); PF1my = *(const float2*)(yp + mcol);
        PF1hx = *(const float2*)(xp + hcolC); PF1hy = *(const float2*)(yp + hcolC);
    }
    {
        const int rl = r0 - 3;
        VM2 = ((unsigned)rl < 512u) ? 1.f : 0.f;
        const int rlc = (rl < 0) ? 0 : rl;
        const float* xp = xplane + (rlc << 9);
        const float* yp = yplane + (rlc << 9);
        PF2mx = *(const float2*)(xp + mcol); PF2my = *(const float2*)(yp + mcol);
        PF2hx = *(const float2*)(xp + hcolC); PF2hy = *(const float2*)(yp + hcolC);
    }

    float tsx = 0.f, tsy = 0.f;
    const float C1 = 1e-4f, C2 = 9e-4f;

    // 75 steps = 25 x 3 (PF ring period); emits for i in [10,74)
    #pragma unroll 1
    for (int it = 0; it < 25; ++it) {
        const int i0 = it * 3;
        STEP(i0 + 0, 0, 1)
        STEP(i0 + 1, 1, 2)
        STEP(i0 + 2, 2, 0)
    }

    // ---- block partial -> global; last block reduces all ----
    float t = tsx + tsy;
    #pragma unroll
    for (int off = 32; off > 0; off >>= 1) t += __shfl_down(t, off, 64);
    __shared__ float wsum[4];
    __shared__ int   sflag;
    if (lane == 0) wsum[wv] = t;
    __syncthreads();
    if (tid == 0) {
        partials[blockIdx.x] = (wsum[0] + wsum[1]) + (wsum[2] + wsum[3]);
        __threadfence();
        const unsigned old = atomicAdd(counter, 1u);
        sflag = (old == NBLK - 1) ? 1 : 0;
    }
    __syncthreads();
    if (sflag) {
        __threadfence();
        double s = 0.0;
        for (int idx = tid; idx < NBLK; idx += 256) s += (double)partials[idx];
        #pragma unroll
        for (int off = 32; off > 0; off >>= 1) s += __shfl_down(s, off, 64);
        __shared__ double dsum[4];
        if (lane == 0) dsum[wv] = s;
        __syncthreads();
        if (tid == 0)
            out[0] = (float)(((dsum[0] + dsum[1]) + (dsum[2] + dsum[3])) / 25165824.0);
    }
}

extern "C" void kernel_launch(void* const* d_in, const int* in_sizes, int n_in,
                              void* d_out, int out_size, void* d_ws, size_t ws_size,
                              hipStream_t stream)
{
    const float* x = (const float*)d_in[0];
    const float* y = (const float*)d_in[1];
    const float* w = (const float*)d_in[2];
    unsigned* counter = (unsigned*)d_ws;                     // zeroed below
    float* partials   = (float*)((char*)d_ws + 256);         // 768 floats

    hipMemsetAsync(d_ws, 0, 4, stream);                      // capture-safe
    ssim_fused<<<NBLK, 256, 0, stream>>>(x, y, w, counter, partials, (float*)d_out);
}

// Round 3
// 280.733 us; speedup vs baseline: 4.1223x; 2.7963x over previous
//
#include <hip/hip_runtime.h>

// SSIM on (32,3,512,512) f32 — wave-autonomous separable 11-tap streaming.
// R8: (1) shift-register vertical conv (descending FMA chain, period-1 code,
// no rotation unroll -> ~8KB hot body); (2) fully branchless hot loop:
// unconditional clamped loads + multiply-by-validity at consume, so the
// waitcnt pass keeps precise vmcnt and the depth-3 register prefetch ring
// actually pipelines; (3) LDS packed float4 (xA,xB,yA,yB) -> 7
// ds_read_b128/step; (4) 256-thread blocks = 4 wave-private bands.
// Each wave: 128 cols x 64 rows; lanes hold 2 cols. No hot-loop barriers.
// R9  FAILED: (256,4) -> allocator targeted 8 waves/EU, VGPR 64, 3GB spill.
// R10 FAILED: (256,3) -> allocator targeted 6 waves/EU (VGPR 84!), still
//             spilled. Any 2nd-arg >= 3 makes the allocator overshoot.
// R11: VALUBusy arithmetic says R0 (VGPR=120, (256,2)) ran only 2 blocks/CU
// (2 waves/SIMD x 27% duty = 54% ~ measured 51%; 3 waves would give ~82%).
// Resources permit 4 blocks/CU at 120 regs, so the ",2" is acting as a CAP.
// Fix: __launch_bounds__(256) + amdgpu_waves_per_eu(2,4): min=2 keeps the
// exact 256-reg budget that produced the spill-free 120-reg codegen; max=4
// removes the 2-wave clamp so HW can co-resident all 768 blocks (3/CU).

#define NBLK 768

__device__ __forceinline__ float2 f2z() { return make_float2(0.f, 0.f); }
__device__ __forceinline__ float2 fma2(float s, float2 a, float2 c) {
    return make_float2(fmaf(s, a.x, c.x), fmaf(s, a.y, c.y));
}
__device__ __forceinline__ float2 mul2(float s, float2 a) {
    return make_float2(s * a.x, s * a.y);
}

// ---- vertical shift-register chains: 10 regs x 5 quantities (float2 A/B) ----
#define DECL_CH(C) float2 C##0=f2z(),C##1=f2z(),C##2=f2z(),C##3=f2z(),C##4=f2z(), \
                          C##5=f2z(),C##6=f2z(),C##7=f2z(),C##8=f2z(),C##9=f2z();
// descending: each reads the not-yet-overwritten lower element
#define SHIFT(C, H) \
  C##9 = fma2(g9, H, C##8); C##8 = fma2(g8, H, C##7); C##7 = fma2(g7, H, C##6); \
  C##6 = fma2(g6, H, C##5); C##5 = fma2(g5, H, C##4); C##4 = fma2(g4, H, C##3); \
  C##3 = fma2(g3, H, C##2); C##2 = fma2(g2, H, C##1); C##1 = fma2(g1, H, C##0); \
  C##0 = mul2(g0, H);

// ---- horizontal tap J: colA uses val[J+1], colB val[J+2] ----
#define HTAP(J, UA, UB) { const float gj = g##J; \
  { const float xv = XV##UA, yv = YV##UA; const float t1 = gj*xv, t2 = gj*yv; \
    HX.x += t1; HY.x += t2; HXX.x = fmaf(t1,xv,HXX.x); HYY.x = fmaf(t2,yv,HYY.x); HXY.x = fmaf(t1,yv,HXY.x); } \
  { const float xv = XV##UB, yv = YV##UB; const float t1 = gj*xv, t2 = gj*yv; \
    HX.y += t1; HY.y += t2; HXX.y = fmaf(t1,xv,HXX.y); HYY.y = fmaf(t2,yv,HYY.y); HXY.y = fmaf(t1,yv,HXY.y); } }

#define SSIM_COL(MU_X, MU_Y, SXX, SYY, SXY, TS) { \
  const float mux = MU_X, muy = MU_Y; \
  const float mux2 = mux*mux, muy2 = muy*muy, muxy = mux*muy; \
  const float vvx = SXX - mux2, vvy = SYY - muy2, vxy = SXY - muxy; \
  const float num = fmaf(2.f, muxy, C1) * fmaf(2.f, vxy, C2); \
  const float den = (mux2 + muy2 + C1) * (vvx + vvy + C2); \
  TS += num * __builtin_amdgcn_rcpf(den); }

// One step: issue PF slot P (row r0-2+i), compute h-conv of current LDS row,
// chain-shift, emit if 10<=i<74, then store PF slot Q (issued 2 steps ago).
#define STEP(I, P, Q) { \
  const int i_ = (I); \
  const int rl = r0 - 2 + i_; \
  VM##P = ((unsigned)rl < 512u) ? 1.f : 0.f; \
  { const int rlc = (rl < 0) ? 0 : ((rl > 511) ? 511 : rl); \
    const float* xp = xplane + (rlc << 9); \
    const float* yp = yplane + (rlc << 9); \
    PF##P##mx = *(const float2*)(xp + mcol); PF##P##my = *(const float2*)(yp + mcol); \
    PF##P##hx = *(const float2*)(xp + hcolC); PF##P##hy = *(const float2*)(yp + hcolC); } \
  const float4 q0 = lsw[lane  ], q1 = lsw[lane+1], q2 = lsw[lane+2], q3 = lsw[lane+3]; \
  const float4 q4 = lsw[lane+4], q5 = lsw[lane+5], q6 = lsw[lane+6]; \
  const float XV1 = q0.y, XV2 = q1.x, XV3 = q1.y, XV4 = q2.x, XV5 = q2.y, XV6 = q3.x; \
  const float XV7 = q3.y, XV8 = q4.x, XV9 = q4.y, XV10 = q5.x, XV11 = q5.y, XV12 = q6.x; \
  const float YV1 = q0.w, YV2 = q1.z, YV3 = q1.w, YV4 = q2.z, YV5 = q2.w, YV6 = q3.z; \
  const float YV7 = q3.w, YV8 = q4.z, YV9 = q4.w, YV10 = q5.z, YV11 = q5.w, YV12 = q6.z; \
  float2 HX = f2z(), HY = f2z(), HXX = f2z(), HYY = f2z(), HXY = f2z(); \
  HTAP(0,1,2)  HTAP(1,2,3)  HTAP(2,3,4)  HTAP(3,4,5)  HTAP(4,5,6)  HTAP(5,6,7) \
  HTAP(6,7,8)  HTAP(7,8,9)  HTAP(8,9,10) HTAP(9,10,11) HTAP(10,11,12) \
  if (i_ >= 10 && i_ < 74) { \
    const float2 EX  = fma2(g10, HX , CX9 ); \
    const float2 EY  = fma2(g10, HY , CY9 ); \
    const float2 EXX = fma2(g10, HXX, CXX9); \
    const float2 EYY = fma2(g10, HYY, CYY9); \
    const float2 EXY = fma2(g10, HXY, CXY9); \
    SSIM_COL(EX.x, EY.x, EXX.x, EYY.x, EXY.x, tsx) \
    SSIM_COL(EX.y, EY.y, EXX.y, EYY.y, EXY.y, tsy) \
  } \
  SHIFT(CX, HX) SHIFT(CY, HY) SHIFT(CXX, HXX) SHIFT(CYY, HYY) SHIFT(CXY, HXY) \
  { const float fq = VM##Q; const float fh = fq * hmask; \
    const float2 wmx = mul2(fq, PF##Q##mx), wmy = mul2(fq, PF##Q##my); \
    const float2 whx = mul2(fh, PF##Q##hx), why = mul2(fh, PF##Q##hy); \
    lsw[lane + 3] = make_float4(wmx.x, wmx.y, wmy.x, wmy.y); \
    if (lane < 6) lsw[hslot] = make_float4(whx.x, whx.y, why.x, why.y); } }

__global__ __launch_bounds__(256)
__attribute__((amdgpu_waves_per_eu(2, 4)))
void ssim_fused(
    const float* __restrict__ x, const float* __restrict__ y,
    const float* __restrict__ window,
    unsigned* __restrict__ counter, float* __restrict__ partials,
    float* __restrict__ out)
{
    const int tid  = threadIdx.x;
    const int lane = tid & 63;
    const int wv   = tid >> 6;
    const int W    = blockIdx.x * 4 + wv;   // 0..3071
    const int img  = W >> 5;                // 96 planes
    const int cb   = (W >> 3) & 3;          // 4 col bands x 128
    const int rb   = W & 7;                 // 8 row bands x 64
    const int r0   = rb << 6;
    const int c0   = cb << 7;

    const float* xplane = x + (size_t)img * 262144;
    const float* yplane = y + (size_t)img * 262144;

    // halo geometry (time-invariant): slots 0..2 left, 67..69 right
    const int  hslot = (lane < 3) ? lane : (64 + lane);
    const int  hcol  = (lane < 3) ? (c0 - 6 + 2 * lane)
                                  : (c0 + 128 + 2 * (lane - 3));
    const float hmask = (lane < 6 && hcol >= 0 && hcol < 511) ? 1.f : 0.f;
    const int  hcolC = (hcol < 0) ? 0 : ((hcol > 510) ? 510 : hcol);
    const int  mcol  = c0 + 2 * lane;

    // 1-D gaussian (row sums of outer(g,g)); uniform -> SGPR via readfirstlane
    float gtmp[11];
    #pragma unroll
    for (int ii = 0; ii < 11; ++ii) {
        float s = 0.f;
        #pragma unroll
        for (int jj = 0; jj < 11; ++jj) s += window[ii * 11 + jj];
        gtmp[ii] = s;
    }
    #define SG(N) const float g##N = __uint_as_float(__builtin_amdgcn_readfirstlane(__float_as_uint(gtmp[N])));
    SG(0) SG(1) SG(2) SG(3) SG(4) SG(5) SG(6) SG(7) SG(8) SG(9) SG(10)

    // wave-private LDS row: slot k = float4(xA,xB,yA,yB) for cols c0-6+2k,+1
    __shared__ float4 ls4[4][72];
    float4* lsw = ls4[wv];

    DECL_CH(CX) DECL_CH(CY) DECL_CH(CXX) DECL_CH(CYY) DECL_CH(CXY)

    // prefetch ring state
    float2 PF0mx, PF0my, PF0hx, PF0hy; float VM0 = 0.f;
    float2 PF1mx, PF1my, PF1hx, PF1hy; float VM1;
    float2 PF2mx, PF2my, PF2hx, PF2hy; float VM2;

    // prime LDS with row r0-5 (read at step 0)
    {
        const int rl = r0 - 5;
        const float fq = ((unsigned)rl < 512u) ? 1.f : 0.f;
        const int rlc = (rl < 0) ? 0 : rl;
        const float* xp = xplane + (rlc << 9);
        const float* yp = yplane + (rlc << 9);
        const float2 mx = *(const float2*)(xp + mcol), my = *(const float2*)(yp + mcol);
        const float2 hx = *(const float2*)(xp + hcolC), hy = *(const float2*)(yp + hcolC);
        const float fh = fq * hmask;
        const float2 wmx = mul2(fq, mx), wmy = mul2(fq, my);
        const float2 whx = mul2(fh, hx), why = mul2(fh, hy);
        lsw[lane + 3] = make_float4(wmx.x, wmx.y, wmy.x, wmy.y);
        if (lane < 6) lsw[hslot] = make_float4(whx.x, whx.y, why.x, why.y);
    }
    // prime PF1 <- row r0-4 (stored end of step 0), PF2 <- row r0-3 (step 1)
    {
        const int rl = r0 - 4;
        VM1 = ((unsigned)rl < 512u) ? 1.f : 0.f;
        const int rlc = (rl < 0) ? 0 : rl;
        const float* xp = xplane + (rlc << 9);
        const float* yp = yplane + (rlc << 9);
        PF1mx = *(const float2*)(xp + mcol); PF1my = *(const float2*)(yp + mcol);
        PF1hx = *(const float2*)(xp + hcolC); PF1hy = *(const float2*)(yp + hcolC);
    }
    {
        const int rl = r0 - 3;
        VM2 = ((unsigned)rl < 512u) ? 1.f : 0.f;
        const int rlc = (rl < 0) ? 0 : rl;
        const float* xp = xplane + (rlc << 9);
        const float* yp = yplane + (rlc << 9);
        PF2mx = *(const float2*)(xp + mcol); PF2my = *(const float2*)(yp + mcol);
        PF2hx = *(const float2*)(xp + hcolC); PF2hy = *(const float2*)(yp + hcolC);
    }

    float tsx = 0.f, tsy = 0.f;
    const float C1 = 1e-4f, C2 = 9e-4f;

    // 75 steps = 25 x 3 (PF ring period); emits for i in [10,74)
    #pragma unroll 1
    for (int it = 0; it < 25; ++it) {
        const int i0 = it * 3;
        STEP(i0 + 0, 0, 1)
        STEP(i0 + 1, 1, 2)
        STEP(i0 + 2, 2, 0)
    }

    // ---- block partial -> global; last block reduces all ----
    float t = tsx + tsy;
    #pragma unroll
    for (int off = 32; off > 0; off >>= 1) t += __shfl_down(t, off, 64);
    __shared__ float wsum[4];
    __shared__ int   sflag;
    if (lane == 0) wsum[wv] = t;
    __syncthreads();
    if (tid == 0) {
        partials[blockIdx.x] = (wsum[0] + wsum[1]) + (wsum[2] + wsum[3]);
        __threadfence();
        const unsigned old = atomicAdd(counter, 1u);
        sflag = (old == NBLK - 1) ? 1 : 0;
    }
    __syncthreads();
    if (sflag) {
        __threadfence();
        double s = 0.0;
        for (int idx = tid; idx < NBLK; idx += 256) s += (double)partials[idx];
        #pragma unroll
        for (int off = 32; off > 0; off >>= 1) s += __shfl_down(s, off, 64);
        __shared__ double dsum[4];
        if (lane == 0) dsum[wv] = s;
        __syncthreads();
        if (tid == 0)
            out[0] = (float)(((dsum[0] + dsum[1]) + (dsum[2] + dsum[3])) / 25165824.0);
    }
}

extern "C" void kernel_launch(void* const* d_in, const int* in_sizes, int n_in,
                              void* d_out, int out_size, void* d_ws, size_t ws_size,
                              hipStream_t stream)
{
    const float* x = (const float*)d_in[0];
    const float* y = (const float*)d_in[1];
    const float* w = (const float*)d_in[2];
    unsigned* counter = (unsigned*)d_ws;                     // zeroed below
    float* partials   = (float*)((char*)d_ws + 256);         // 768 floats

    hipMemsetAsync(d_ws, 0, 4, stream);                      // capture-safe
    ssim_fused<<<NBLK, 256, 0, stream>>>(x, y, w, counter, partials, (float*)d_out);
}